// Round 4
// baseline (217.533 us; speedup 1.0000x reference)
//
#include <hip/hip_runtime.h>

#define SEQ 128
#define BATCH 512
#define IN_DIM 128
#define HID 128
#define NCH 2   // independent batch-element chains per wave

typedef float vf2 __attribute__((ext_vector_type(2)));

#define LOG2E 1.4426950408889634f
#define INV2PI 0.15915494309189535f

__device__ __forceinline__ float rcp_f(float x) { return __builtin_amdgcn_rcpf(x); }
// Guaranteed-native transcendentals (single VOP1 each).
__device__ __forceinline__ float exp2_f(float x) { float r; asm("v_exp_f32 %0, %1" : "=v"(r) : "v"(x)); return r; }
__device__ __forceinline__ float sin2pi_f(float x) { float r; asm("v_sin_f32 %0, %1" : "=v"(r) : "v"(x)); return r; }
__device__ __forceinline__ float cos2pi_f(float x) { float r; asm("v_cos_f32 %0, %1" : "=v"(r) : "v"(x)); return r; }
__device__ __forceinline__ float tanh_f(float x) {
  // tanh(x) = 1 - 2/(exp2(x*2log2e)+1)
  return 1.0f - 2.0f * rcp_f(exp2_f(x * 2.885390082f) + 1.0f);
}

template <int CTRL>
__device__ __forceinline__ float dpp_add(float s) {
  return s + __int_as_float(__builtin_amdgcn_mov_dpp(__float_as_int(s), CTRL, 0xF, 0xF, true));
}
__device__ __forceinline__ float rdlane(float v, int src) {
  return __int_as_float(__builtin_amdgcn_readlane(__float_as_int(v), src));
}

// ONE WAVE handles NCH=2 independent batch elements (chains).  All weights /
// TM constants are batch-independent -> shared registers; per-chain state is
// ~21 VGPRs.  The two chains' serial dependency graphs interleave in one
// instruction stream, filling each other's latency stalls (the R0-R3 invariant
// showed the step is dep-latency bound on a solo wave, not issue bound).
// All per-chain loops below are fully unrolled -> constant indices -> registers.
__global__ __launch_bounds__(64) void qlstm_kernel(
    const float* __restrict__ X, const float* __restrict__ Wq, const float* __restrict__ bq,
    const float* __restrict__ pf, const float* __restrict__ pi_, const float* __restrict__ pg,
    const float* __restrict__ po, const float* __restrict__ Wf, const float* __restrict__ bf,
    const float* __restrict__ Wi, const float* __restrict__ bi, const float* __restrict__ Wg,
    const float* __restrict__ bg, const float* __restrict__ Wo, const float* __restrict__ bo,
    float* __restrict__ out)
{
  __shared__ __align__(16) float gsh[NCH][4 * HID];
  __shared__ __align__(16) float h_sh[NCH][HID];

  const int lane = threadIdx.x;
  const int r = lane >> 3, c = lane & 7;         // dot roles: wire r, dims 16c..16c+15
  const int g = lane >> 4, p = lane & 15;        // gate roles: gate g, dims 8p..8p+7
  const int b0 = blockIdx.x * NCH;

  const float* gW = (g == 0) ? Wf : (g == 1) ? Wi : (g == 2) ? Wg : Wo;
  const float* gB = (g == 0) ? bf : (g == 1) ? bi : (g == 2) ? bg : bo;
  const float* gP = (g == 0) ? pf : (g == 1) ? pi_ : (g == 2) ? pg : po;

  // ---- shared (batch-independent) register preloads ----
  // INV2PI folded into wx/wh/bq: z*INV2PI computed implicitly by the dot.
  vf2 wx[8], wh[8];
  {
    const vf2* pxw = (const vf2*)(Wq + r * 256 + 16 * c);
    const vf2* phw = (const vf2*)(Wq + r * 256 + 128 + 16 * c);
#pragma unroll
    for (int j = 0; j < 8; ++j) { wx[j] = pxw[j] * INV2PI; wh[j] = phw[j] * INV2PI; }
  }
  const float bqv = bq[r] * INV2PI;

  const float amul = (g == 2) ? 2.0f : 1.0f;     // tanh = 2*sigmoid(2x)-1
  const float oadd = (g == 2) ? -1.0f : 0.0f;
  const float ksc  = -amul * LOG2E;              // fold into gate weights: act = exp2(acc)

  vf2 wg2[8][4];
#pragma unroll
  for (int w = 0; w < 8; ++w)
#pragma unroll
    for (int j = 0; j < 4; ++j) {
      wg2[w][j].x = gW[(8 * p + 2 * j)     * 8 + w] * ksc;
      wg2[w][j].y = gW[(8 * p + 2 * j + 1) * 8 + w] * ksc;
    }
  vf2 bias2[4];
#pragma unroll
  for (int j = 0; j < 4; ++j) {
    bias2[j].x = gB[8 * p + 2 * j]     * ksc;
    bias2[j].y = gB[8 * p + 2 * j + 1] * ksc;
  }
  vf2 cbsb[8]; float C1[8], S1[8];
#pragma unroll
  for (int w = 0; w < 8; ++w) {
    float th0 = gP[w], th1 = gP[8 + w];
    cbsb[w].x = cosf(th0); cbsb[w].y = sinf(th0);
    C1[w] = cosf(th1); S1[w] = sinf(th1);
  }

  // ---- per-chain state ----
  vf2 c2[NCH], h2v[NCH];
  float4 hh[NCH][4];
  float xp_cur[NCH];
  const float* xg[NCH];
  float* outp[NCH];
#pragma unroll
  for (int e = 0; e < NCH; ++e) {
    c2[e].x = 0.f; c2[e].y = 0.f;
    h2v[e].x = 0.f; h2v[e].y = 0.f;
#pragma unroll
    for (int j = 0; j < 4; ++j) { hh[e][j].x = 0.f; hh[e][j].y = 0.f; hh[e][j].z = 0.f; hh[e][j].w = 0.f; }
    xg[e]   = X   + (size_t)(b0 + e) * IN_DIM + 16 * c;
    outp[e] = out + (size_t)(b0 + e) * HID + 2 * lane;
    // xp for t=0 (scaled weights -> already includes INV2PI)
    const float4* x0_ = (const float4*)xg[e];
    float4 a0 = x0_[0], a1 = x0_[1], a2 = x0_[2], a3 = x0_[3];
    vf2 ax = wx[0] * (vf2){a0.x, a0.y} + wx[1] * (vf2){a0.z, a0.w}
           + wx[2] * (vf2){a1.x, a1.y} + wx[3] * (vf2){a1.z, a1.w}
           + wx[4] * (vf2){a2.x, a2.y} + wx[5] * (vf2){a2.z, a2.w}
           + wx[6] * (vf2){a3.x, a3.y} + wx[7] * (vf2){a3.z, a3.w};
    xp_cur[e] = ax.x + ax.y;
  }

#pragma unroll 1
  for (int t = 0; t < SEQ; ++t) {
    // ---- chain head: q_in dot (h part + precomputed x partial), 8-lane DPP reduce ----
    float zz[NCH];
#pragma unroll
    for (int e = 0; e < NCH; ++e) {
      vf2 aq = (vf2){xp_cur[e], 0.0f}
             + wh[0] * (vf2){hh[e][0].x, hh[e][0].y} + wh[1] * (vf2){hh[e][0].z, hh[e][0].w}
             + wh[2] * (vf2){hh[e][1].x, hh[e][1].y} + wh[3] * (vf2){hh[e][1].z, hh[e][1].w}
             + wh[4] * (vf2){hh[e][2].x, hh[e][2].y} + wh[5] * (vf2){hh[e][2].z, hh[e][2].w}
             + wh[6] * (vf2){hh[e][3].x, hh[e][3].y} + wh[7] * (vf2){hh[e][3].z, hh[e][3].w};
      float s_ = aq.x + aq.y;
      s_ = dpp_add<0xB1>(s_); s_ = dpp_add<0x4E>(s_); s_ = dpp_add<0x141>(s_);
      zz[e] = s_ + bqv;                      // already in revolutions
    }
    float szv[NCH], czv[NCH];
#pragma unroll
    for (int e = 0; e < NCH; ++e) { szv[e] = sin2pi_f(zz[e]); czv[e] = cos2pi_f(zz[e]); }

    // ---- transient X(t+1) loads (consumed at step tail; ~full chain to cover latency) ----
    float4 xl[NCH][4];
    {
      const int tn = (t + 1 < SEQ) ? t + 1 : SEQ - 1;
#pragma unroll
      for (int e = 0; e < NCH; ++e) {
        const float4* xn_ = (const float4*)(xg[e] + (size_t)tn * (BATCH * IN_DIM));
#pragma unroll
        for (int j = 0; j < 4; ++j) xl[e][j] = xn_[j];
      }
    }

    // ---- broadcast (c,s) of all 8 wires via readlane -> SGPRs ----
    float cqs[NCH][8], sqs[NCH][8];
#pragma unroll
    for (int e = 0; e < NCH; ++e)
#pragma unroll
      for (int w = 0; w < 8; ++w) {
        cqs[e][w] = rdlane(czv[e], 8 * w);
        sqs[e][w] = rdlane(szv[e], 8 * w);
      }

    // ---- TM chain + fused gate GEMM (both chains interleaved) ----
    vf2 acc[NCH][4];
    float u_[NCH], d_[NCH], P_[NCH], R_[NCH];
#pragma unroll
    for (int e = 0; e < NCH; ++e) {
      acc[e][0] = bias2[0]; acc[e][1] = bias2[1]; acc[e][2] = bias2[2]; acc[e][3] = bias2[3];
      vf2 KA0 = cbsb[0] * cqs[e][0];
      u_[e] = C1[0]; d_[e] = C1[0] * KA0.x;
      P_[e] = -S1[0] * KA0.y; R_[e] = -S1[0] * sqs[e][0];
    }
#pragma unroll
    for (int w = 1; w < 8; ++w) {
#pragma unroll
      for (int e = 0; e < NCH; ++e) {
        vf2 KA = cbsb[w] * cqs[e][w];
        float K_ = KA.x, A2_ = KA.y, B2_ = sqs[e][w];
        float Md = fmaf(A2_, P_[e], d_[e]);
        float MP = fmaf(A2_, d_[e], P_[e]);
        float Mu = fmaf(K_, u_[e], -(B2_ * R_[e]));
        float MR = fmaf(B2_, u_[e], K_ * R_[e]);
        acc[e][0] += Md * wg2[w - 1][0]; acc[e][1] += Md * wg2[w - 1][1];
        acc[e][2] += Md * wg2[w - 1][2]; acc[e][3] += Md * wg2[w - 1][3];
        u_[e] = C1[w] * Md; d_[e] = C1[w] * Mu;
        P_[e] = -S1[w] * MP; R_[e] = -S1[w] * MR;
      }
    }
#pragma unroll
    for (int e = 0; e < NCH; ++e) {
      float ev7_ = d_[e] + P_[e];
      acc[e][0] += ev7_ * wg2[7][0]; acc[e][1] += ev7_ * wg2[7][1];
      acc[e][2] += ev7_ * wg2[7][2]; acc[e][3] += ev7_ * wg2[7][3];
    }

    // ---- activation (bare exp2; scale folded) + gate publish ----
#pragma unroll
    for (int e = 0; e < NCH; ++e) {
      float av_[8] = {acc[e][0].x, acc[e][0].y, acc[e][1].x, acc[e][1].y,
                      acc[e][2].x, acc[e][2].y, acc[e][3].x, acc[e][3].y};
      float o8[8];
#pragma unroll
      for (int k = 0; k < 8; ++k) {
        float ex_ = exp2_f(av_[k]);
        o8[k] = fmaf(rcp_f(1.0f + ex_), amul, oadd);
      }
      float4* gp4 = (float4*)(&gsh[e][g * HID + 8 * p]);
      float4 w0; w0.x = o8[0]; w0.y = o8[1]; w0.z = o8[2]; w0.w = o8[3];
      float4 w1; w1.x = o8[4]; w1.y = o8[5]; w1.z = o8[6]; w1.w = o8[7];
      gp4[0] = w0; gp4[1] = w1;
    }

    // ---- cell update (dims 2*lane, 2*lane+1); in-wave DS ordering ----
#pragma unroll
    for (int e = 0; e < NCH; ++e) {
      vf2 fv = *(const vf2*)(&gsh[e][0 * HID + 2 * lane]);
      vf2 iv = *(const vf2*)(&gsh[e][1 * HID + 2 * lane]);
      vf2 gv = *(const vf2*)(&gsh[e][2 * HID + 2 * lane]);
      vf2 ov = *(const vf2*)(&gsh[e][3 * HID + 2 * lane]);
      c2[e] = fv * c2[e] + iv * gv;
      h2v[e].x = ov.x * tanh_f(c2[e].x);
      h2v[e].y = ov.y * tanh_f(c2[e].y);
      *(vf2*)(&h_sh[e][2 * lane]) = h2v[e];
    }
    // issue next-step h reads immediately (latency overlaps stores + loop tail)
#pragma unroll
    for (int e = 0; e < NCH; ++e) {
      const float4* hp4 = (const float4*)(&h_sh[e][16 * c]);
      hh[e][0] = hp4[0]; hh[e][1] = hp4[1]; hh[e][2] = hp4[2]; hh[e][3] = hp4[3];
    }
    // output stores
#pragma unroll
    for (int e = 0; e < NCH; ++e)
      *(vf2*)(outp[e] + (size_t)t * (BATCH * HID)) = h2v[e];

    // ---- off-chain tail: next x-partial from transient loads ----
#pragma unroll
    for (int e = 0; e < NCH; ++e) {
      vf2 axn = wx[0] * (vf2){xl[e][0].x, xl[e][0].y} + wx[1] * (vf2){xl[e][0].z, xl[e][0].w}
              + wx[2] * (vf2){xl[e][1].x, xl[e][1].y} + wx[3] * (vf2){xl[e][1].z, xl[e][1].w}
              + wx[4] * (vf2){xl[e][2].x, xl[e][2].y} + wx[5] * (vf2){xl[e][2].z, xl[e][2].w}
              + wx[6] * (vf2){xl[e][3].x, xl[e][3].y} + wx[7] * (vf2){xl[e][3].z, xl[e][3].w};
      xp_cur[e] = axn.x + axn.y;
    }
  }

  // hx, cx
  {
    size_t base = (size_t)SEQ * BATCH * HID;
#pragma unroll
    for (int e = 0; e < NCH; ++e) {
      *(vf2*)(out + base + (size_t)(b0 + e) * HID + 2 * lane) = h2v[e];
      *(vf2*)(out + base + (size_t)BATCH * HID + (size_t)(b0 + e) * HID + 2 * lane) = c2[e];
    }
  }
}

extern "C" void kernel_launch(void* const* d_in, const int* in_sizes, int n_in,
                              void* d_out, int out_size, void* d_ws, size_t ws_size,
                              hipStream_t stream) {
  (void)in_sizes; (void)n_in; (void)out_size; (void)d_ws; (void)ws_size;
  const float* X   = (const float*)d_in[0];
  const float* Wq  = (const float*)d_in[1];
  const float* bq  = (const float*)d_in[2];
  const float* pf  = (const float*)d_in[3];
  const float* pi_ = (const float*)d_in[4];
  const float* pg  = (const float*)d_in[5];
  const float* po  = (const float*)d_in[6];
  const float* Wf  = (const float*)d_in[7];
  const float* bf  = (const float*)d_in[8];
  const float* Wi  = (const float*)d_in[9];
  const float* bi  = (const float*)d_in[10];
  const float* Wg  = (const float*)d_in[11];
  const float* bg  = (const float*)d_in[12];
  const float* Wo  = (const float*)d_in[13];
  const float* bo  = (const float*)d_in[14];
  float* out = (float*)d_out;

  qlstm_kernel<<<BATCH / NCH, 64, 0, stream>>>(X, Wq, bq, pf, pi_, pg, po,
                                               Wf, bf, Wi, bi, Wg, bg, Wo, bo, out);
}

// Round 5
// 214.630 us; speedup vs baseline: 1.0135x; 1.0135x over previous
//
#include <hip/hip_runtime.h>

#define SEQ 128
#define BATCH 512
#define IN_DIM 128
#define HID 128

typedef float vf2 __attribute__((ext_vector_type(2)));

#define LOG2E 1.4426950408889634f
#define INV2PI 0.15915494309189535f

__device__ __forceinline__ float rcp_f(float x) { return __builtin_amdgcn_rcpf(x); }
// Guaranteed-native transcendentals (single VOP1 each).
__device__ __forceinline__ float exp2_f(float x) { float r; asm("v_exp_f32 %0, %1" : "=v"(r) : "v"(x)); return r; }
__device__ __forceinline__ float sin2pi_f(float x) { float r; asm("v_sin_f32 %0, %1" : "=v"(r) : "v"(x)); return r; }
__device__ __forceinline__ float cos2pi_f(float x) { float r; asm("v_cos_f32 %0, %1" : "=v"(r) : "v"(x)); return r; }
__device__ __forceinline__ float tanh_f(float x) {
  // tanh(x) = 1 - 2/(exp2(x*2log2e)+1)
  return 1.0f - 2.0f * rcp_f(exp2_f(x * 2.885390082f) + 1.0f);
}

template <int CTRL>
__device__ __forceinline__ float dpp_add(float s) {
  return s + __int_as_float(__builtin_amdgcn_mov_dpp(__float_as_int(s), CTRL, 0xF, 0xF, true));
}
__device__ __forceinline__ float rdlane(float v, int src) {
  return __int_as_float(__builtin_amdgcn_readlane(__float_as_int(v), src));
}

// From register x whose 16-lane quarters hold [q0,q1,q2,q3], give EVERY lane
// (q0,q1,q2,q3) at its own p = lane&15.  Pure VALU cross-lane (validated R1).
__device__ __forceinline__ void quarter_bcast(float x, float& r0, float& r1, float& r2, float& r3) {
  unsigned xu = __float_as_uint(x);
  auto pr = __builtin_amdgcn_permlane32_swap(xu, xu, false, false);
#if __has_builtin(__builtin_amdgcn_permlane16_swap)
  auto lo = __builtin_amdgcn_permlane16_swap(pr[0], pr[0], false, false);
  auto hi = __builtin_amdgcn_permlane16_swap(pr[1], pr[1], false, false);
  r0 = __uint_as_float(lo[0]); r1 = __uint_as_float(lo[1]);
  r2 = __uint_as_float(hi[0]); r3 = __uint_as_float(hi[1]);
#else
  unsigned s0 = (unsigned)__builtin_amdgcn_ds_swizzle((int)pr[0], 0x401F);
  unsigned s1 = (unsigned)__builtin_amdgcn_ds_swizzle((int)pr[1], 0x401F);
  const bool qo = (threadIdx.x >> 4) & 1;
  r0 = __uint_as_float(qo ? s0 : pr[0]);
  r1 = __uint_as_float(qo ? pr[0] : s0);
  r2 = __uint_as_float(qo ? s1 : pr[1]);
  r3 = __uint_as_float(qo ? pr[1] : s1);
#endif
}

// ONE WAVE per batch element (R3 skeleton), chain shortened:
//  - gate exchange via permlane rounds + cndmask (no gate LDS round trip; gsh gone).
//    Cell ownership: lane (g,p) owns dims D0=8p+2g, D0+1, so the needed act
//    values are exactly round j==g of a 4-round quarter_bcast.
//  - h-dot tree-reassociated (halved FMA chain depth).
//  - X(t+1) loads issued at step head (full-step latency cover); xp tail computed
//    before the output store so its vmcnt wait covers loads only.
//  - h exchange stays in LDS (1 trip): write b64 at D0, read 4xb128 at 16c,
//    reads issued immediately after the write (in-wave DS ordering).
__global__ __launch_bounds__(64) void qlstm_kernel(
    const float* __restrict__ X, const float* __restrict__ Wq, const float* __restrict__ bq,
    const float* __restrict__ pf, const float* __restrict__ pi_, const float* __restrict__ pg,
    const float* __restrict__ po, const float* __restrict__ Wf, const float* __restrict__ bf,
    const float* __restrict__ Wi, const float* __restrict__ bi, const float* __restrict__ Wg,
    const float* __restrict__ bg, const float* __restrict__ Wo, const float* __restrict__ bo,
    float* __restrict__ out)
{
  __shared__ __align__(16) float h_sh[HID];

  const int lane = threadIdx.x;
  const int r = lane >> 3, c = lane & 7;         // dot roles: wire r, dims 16c..16c+15
  const int g = lane >> 4, p = lane & 15;        // gate roles: gate g, act dims 8p..8p+7
  const int b = blockIdx.x;
  const int D0 = 8 * p + 2 * g;                  // cell-owned dims D0, D0+1
  const bool gsel1 = (g & 1);                    // loop-invariant select masks
  const bool gsel2 = (g >= 2);

  const float* gW = (g == 0) ? Wf : (g == 1) ? Wi : (g == 2) ? Wg : Wo;
  const float* gB = (g == 0) ? bf : (g == 1) ? bi : (g == 2) ? bg : bo;
  const float* gP = (g == 0) ? pf : (g == 1) ? pi_ : (g == 2) ? pg : po;

  // ---- one-time register preloads (INV2PI folded into wx/wh/bq) ----
  vf2 wx[8], wh[8];
  {
    const vf2* pxw = (const vf2*)(Wq + r * 256 + 16 * c);
    const vf2* phw = (const vf2*)(Wq + r * 256 + 128 + 16 * c);
#pragma unroll
    for (int j = 0; j < 8; ++j) { wx[j] = pxw[j] * INV2PI; wh[j] = phw[j] * INV2PI; }
  }
  const float bqv = bq[r] * INV2PI;

  const float amul = (g == 2) ? 2.0f : 1.0f;     // tanh = 2*sigmoid(2x)-1
  const float oadd = (g == 2) ? -1.0f : 0.0f;
  const float ksc  = -amul * LOG2E;              // folded: act = exp2(acc)

  vf2 wg2[8][4];
#pragma unroll
  for (int w = 0; w < 8; ++w)
#pragma unroll
    for (int j = 0; j < 4; ++j) {
      wg2[w][j].x = gW[(8 * p + 2 * j)     * 8 + w] * ksc;
      wg2[w][j].y = gW[(8 * p + 2 * j + 1) * 8 + w] * ksc;
    }
  vf2 bias2[4];
#pragma unroll
  for (int j = 0; j < 4; ++j) {
    bias2[j].x = gB[8 * p + 2 * j]     * ksc;
    bias2[j].y = gB[8 * p + 2 * j + 1] * ksc;
  }
  vf2 cbsb[8]; float C1[8], S1[8];
#pragma unroll
  for (int w = 0; w < 8; ++w) {
    float th0 = gP[w], th1 = gP[8 + w];
    cbsb[w].x = cosf(th0); cbsb[w].y = sinf(th0);
    C1[w] = cosf(th1); S1[w] = sinf(th1);
  }

  // state
  vf2 c2; c2.x = 0.f; c2.y = 0.f;
  vf2 h2v; h2v.x = 0.f; h2v.y = 0.f;
  float4 hh0 = {0,0,0,0}, hh1 = {0,0,0,0}, hh2 = {0,0,0,0}, hh3 = {0,0,0,0};

  const float* xg = X + (size_t)b * IN_DIM + 16 * c;
  float* outp = out + (size_t)b * HID + D0;
  const float4* hp4 = (const float4*)(h_sh + 16 * c);

  // xp for t=0
  float xp_cur;
  {
    const float4* x0_ = (const float4*)xg;
    float4 a0 = x0_[0], a1 = x0_[1], a2 = x0_[2], a3 = x0_[3];
    vf2 t0 = wx[0] * (vf2){a0.x, a0.y} + wx[1] * (vf2){a0.z, a0.w};
    vf2 t1 = wx[2] * (vf2){a1.x, a1.y} + wx[3] * (vf2){a1.z, a1.w};
    vf2 t2 = wx[4] * (vf2){a2.x, a2.y} + wx[5] * (vf2){a2.z, a2.w};
    vf2 t3 = wx[6] * (vf2){a3.x, a3.y} + wx[7] * (vf2){a3.z, a3.w};
    vf2 ax = (t0 + t1) + (t2 + t3);
    xp_cur = ax.x + ax.y;
  }

#pragma unroll 1
  for (int t = 0; t < SEQ; ++t) {
    // ---- 0. issue X(t+1) loads first: full-step latency cover ----
    float4 xl0, xl1, xl2, xl3;
    {
      const int tn = (t + 1 < SEQ) ? t + 1 : SEQ - 1;
      const float4* xn_ = (const float4*)(xg + (size_t)tn * (BATCH * IN_DIM));
      xl0 = xn_[0]; xl1 = xn_[1]; xl2 = xn_[2]; xl3 = xn_[3];
    }

    // ---- 1. chain: q_in dot (tree) + row8 DPP reduce + sincos ----
    float zz;
    {
      vf2 t0 = wh[0] * (vf2){hh0.x, hh0.y} + wh[1] * (vf2){hh0.z, hh0.w};
      vf2 t1 = wh[2] * (vf2){hh1.x, hh1.y} + wh[3] * (vf2){hh1.z, hh1.w};
      vf2 t2 = wh[4] * (vf2){hh2.x, hh2.y} + wh[5] * (vf2){hh2.z, hh2.w};
      vf2 t3 = wh[6] * (vf2){hh3.x, hh3.y} + wh[7] * (vf2){hh3.z, hh3.w};
      vf2 aq = ((t0 + t1) + (t2 + t3)) + (vf2){xp_cur, 0.0f};
      float s_ = aq.x + aq.y;
      s_ = dpp_add<0xB1>(s_); s_ = dpp_add<0x4E>(s_); s_ = dpp_add<0x141>(s_);
      zz = s_ + bqv;                      // already in revolutions
    }
    float szv = sin2pi_f(zz), czv = cos2pi_f(zz);

    // ---- 2. broadcast (c,s) of all 8 wires via readlane -> SGPRs ----
    float cqs[8], sqs[8];
#pragma unroll
    for (int w = 0; w < 8; ++w) { cqs[w] = rdlane(czv, 8 * w); sqs[w] = rdlane(szv, 8 * w); }

    // ---- 3. TM chain + fused gate GEMM ----
    vf2 acc0 = bias2[0], acc1 = bias2[1], acc2 = bias2[2], acc3 = bias2[3];
    float u_, d_, P_, R_;
    {
      vf2 KA0 = cbsb[0] * cqs[0];
      u_ = C1[0]; d_ = C1[0] * KA0.x;
      P_ = -S1[0] * KA0.y; R_ = -S1[0] * sqs[0];
    }
#pragma unroll
    for (int w = 1; w < 8; ++w) {
      vf2 KA = cbsb[w] * cqs[w];
      float K_ = KA.x, A2_ = KA.y, B2_ = sqs[w];
      float Md = fmaf(A2_, P_, d_);
      float MP = fmaf(A2_, d_, P_);
      float Mu = fmaf(K_, u_, -(B2_ * R_));
      float MR = fmaf(B2_, u_, K_ * R_);
      acc0 += Md * wg2[w - 1][0]; acc1 += Md * wg2[w - 1][1];
      acc2 += Md * wg2[w - 1][2]; acc3 += Md * wg2[w - 1][3];
      u_ = C1[w] * Md; d_ = C1[w] * Mu;
      P_ = -S1[w] * MP; R_ = -S1[w] * MR;
    }
    float ev7_ = d_ + P_;
    acc0 += ev7_ * wg2[7][0]; acc1 += ev7_ * wg2[7][1];
    acc2 += ev7_ * wg2[7][2]; acc3 += ev7_ * wg2[7][3];

    // ---- 4. activation: bare exp2 (scale folded into weights) ----
    float av_[8] = {acc0.x, acc0.y, acc1.x, acc1.y, acc2.x, acc2.y, acc3.x, acc3.y};
    float o8[8];
#pragma unroll
    for (int k = 0; k < 8; ++k) {
      float e_ = exp2_f(av_[k]);
      o8[k] = fmaf(rcp_f(1.0f + e_), amul, oadd);
    }

    // ---- 5. gate exchange: 4 permlane rounds + round-g selection ----
    // Round j broadcasts (across quarters) acts at dims 8p+2j, 8p+2j+1.
    float rE[4][4], rO[4][4];
#pragma unroll
    for (int j = 0; j < 4; ++j) {
      quarter_bcast(o8[2 * j],     rE[j][0], rE[j][1], rE[j][2], rE[j][3]);
      quarter_bcast(o8[2 * j + 1], rO[j][0], rO[j][1], rO[j][2], rO[j][3]);
    }
    // lane keeps round j == g (its own dims D0, D0+1); quarter q = gate q
    vf2 fv, iv, gv, ov;
    {
      float lo, hi;
#define SEL4(A0, A1, A2, A3, DST) \
      lo = gsel1 ? (A1) : (A0); hi = gsel1 ? (A3) : (A2); DST = gsel2 ? hi : lo;
      SEL4(rE[0][0], rE[1][0], rE[2][0], rE[3][0], fv.x)
      SEL4(rO[0][0], rO[1][0], rO[2][0], rO[3][0], fv.y)
      SEL4(rE[0][1], rE[1][1], rE[2][1], rE[3][1], iv.x)
      SEL4(rO[0][1], rO[1][1], rO[2][1], rO[3][1], iv.y)
      SEL4(rE[0][2], rE[1][2], rE[2][2], rE[3][2], gv.x)
      SEL4(rO[0][2], rO[1][2], rO[2][2], rO[3][2], gv.y)
      SEL4(rE[0][3], rE[1][3], rE[2][3], rE[3][3], ov.x)
      SEL4(rO[0][3], rO[1][3], rO[2][3], rO[3][3], ov.y)
#undef SEL4
    }

    // ---- 6. cell update (dims D0, D0+1) ----
    c2 = fv * c2 + iv * gv;
    h2v.x = ov.x * tanh_f(c2.x);
    h2v.y = ov.y * tanh_f(c2.y);

    // ---- 7. h publish + immediate next-step h reads (in-wave DS ordering) ----
    *(vf2*)(h_sh + D0) = h2v;
    hh0 = hp4[0]; hh1 = hp4[1]; hh2 = hp4[2]; hh3 = hp4[3];

    // ---- 8. xp tail from xl (vmcnt waits only on loads), then output store ----
    {
      vf2 t0 = wx[0] * (vf2){xl0.x, xl0.y} + wx[1] * (vf2){xl0.z, xl0.w};
      vf2 t1 = wx[2] * (vf2){xl1.x, xl1.y} + wx[3] * (vf2){xl1.z, xl1.w};
      vf2 t2 = wx[4] * (vf2){xl2.x, xl2.y} + wx[5] * (vf2){xl2.z, xl2.w};
      vf2 t3 = wx[6] * (vf2){xl3.x, xl3.y} + wx[7] * (vf2){xl3.z, xl3.w};
      vf2 axn = (t0 + t1) + (t2 + t3);
      xp_cur = axn.x + axn.y;
    }
    *(vf2*)(outp + (size_t)t * (BATCH * HID)) = h2v;
  }

  // hx, cx
  {
    size_t base = (size_t)SEQ * BATCH * HID;
    *(vf2*)(out + base + (size_t)b * HID + D0) = h2v;
    *(vf2*)(out + base + (size_t)BATCH * HID + (size_t)b * HID + D0) = c2;
  }
}

extern "C" void kernel_launch(void* const* d_in, const int* in_sizes, int n_in,
                              void* d_out, int out_size, void* d_ws, size_t ws_size,
                              hipStream_t stream) {
  (void)in_sizes; (void)n_in; (void)out_size; (void)d_ws; (void)ws_size;
  const float* X   = (const float*)d_in[0];
  const float* Wq  = (const float*)d_in[1];
  const float* bq  = (const float*)d_in[2];
  const float* pf  = (const float*)d_in[3];
  const float* pi_ = (const float*)d_in[4];
  const float* pg  = (const float*)d_in[5];
  const float* po  = (const float*)d_in[6];
  const float* Wf  = (const float*)d_in[7];
  const float* bf  = (const float*)d_in[8];
  const float* Wi  = (const float*)d_in[9];
  const float* bi  = (const float*)d_in[10];
  const float* Wg  = (const float*)d_in[11];
  const float* bg  = (const float*)d_in[12];
  const float* Wo  = (const float*)d_in[13];
  const float* bo  = (const float*)d_in[14];
  float* out = (float*)d_out;

  qlstm_kernel<<<BATCH, 64, 0, stream>>>(X, Wq, bq, pf, pi_, pg, po,
                                         Wf, bf, Wi, bi, Wg, bg, Wo, bo, out);
}

// Round 6
// 201.604 us; speedup vs baseline: 1.0790x; 1.0646x over previous
//
#include <hip/hip_runtime.h>

#define SEQ 128
#define BATCH 512
#define IN_DIM 128
#define HID 128

typedef float vf2 __attribute__((ext_vector_type(2)));

#define LOG2E 1.4426950408889634f
#define INV2PI 0.15915494309189535f

__device__ __forceinline__ float rcp_f(float x) { return __builtin_amdgcn_rcpf(x); }
// Guaranteed-native transcendentals (single VOP1 each).
__device__ __forceinline__ float exp2_f(float x) { float r; asm("v_exp_f32 %0, %1" : "=v"(r) : "v"(x)); return r; }
__device__ __forceinline__ float sin2pi_f(float x) { float r; asm("v_sin_f32 %0, %1" : "=v"(r) : "v"(x)); return r; }
__device__ __forceinline__ float cos2pi_f(float x) { float r; asm("v_cos_f32 %0, %1" : "=v"(r) : "v"(x)); return r; }
__device__ __forceinline__ float tanh_f(float x) {
  // tanh(x) = 1 - 2/(exp2(x*2log2e)+1)
  return 1.0f - 2.0f * rcp_f(exp2_f(x * 2.885390082f) + 1.0f);
}

template <int CTRL>
__device__ __forceinline__ float dpp_add(float s) {
  return s + __int_as_float(__builtin_amdgcn_mov_dpp(__float_as_int(s), CTRL, 0xF, 0xF, true));
}
template <int CTRL>
__device__ __forceinline__ float dpp_mov(float s) {
  return __int_as_float(__builtin_amdgcn_mov_dpp(__float_as_int(s), CTRL, 0xF, 0xF, true));
}
__device__ __forceinline__ float rdlane(float v, int src) {
  return __int_as_float(__builtin_amdgcn_readlane(__float_as_int(v), src));
}
// Value from lane^32 — pure VALU (permlane32_swap validated in R1).
// pr[0] = lower-32 lanes' values (replicated up), pr[1] = upper-32's (replicated down).
__device__ __forceinline__ float xor32_f(float x, bool hi) {
  unsigned xu = __float_as_uint(x);
  auto pr = __builtin_amdgcn_permlane32_swap(xu, xu, false, false);
  return __uint_as_float(hi ? pr[0] : pr[1]);
}

// ONE WAVE per batch element (R3 skeleton).  Changes vs R3:
//  - gate id remapped to lane bits (b5,b3): all 3 foreign quarters reachable by
//    VALU-only cross-lane (lane^8 = DPP ROW_ROR:8, lane^32 = permlane32_swap,
//    lane^40 = compose).  NO ds_swizzle (R5's fallback trap), NO gate LDS trip.
//  - gate-GEMM weights pre-permuted by xor-distance m (wg2[w][m] <-> dims
//    8p+2(g^m)) so the exchange needs zero send-side selects: send acc pair m,
//    receive exactly your own dims' gate-(g^m) acts.
//  - h tile in LDS with 80-byte lines (16 floats + 16B pad): the 4 b128 reads
//    hit 8 distinct bank-quads (conflict-free); b64 writes ~2-way (free).
//  - TM recursion / GEMM / activation arithmetic bit-identical to R3.
__global__ __launch_bounds__(64) void qlstm_kernel(
    const float* __restrict__ X, const float* __restrict__ Wq, const float* __restrict__ bq,
    const float* __restrict__ pf, const float* __restrict__ pi_, const float* __restrict__ pg,
    const float* __restrict__ po, const float* __restrict__ Wf, const float* __restrict__ bf,
    const float* __restrict__ Wi, const float* __restrict__ bi, const float* __restrict__ Wg,
    const float* __restrict__ bg, const float* __restrict__ Wo, const float* __restrict__ bo,
    float* __restrict__ out)
{
  __shared__ __align__(16) float h_sw[160];   // 8 lines x (16 floats + 16B pad) = 640 B

  const int lane = threadIdx.x;
  const int r = lane >> 3, c = lane & 7;       // dot roles: wire r, dims 16c..16c+15
  const bool b3v = (lane >> 3) & 1;            // gate bit 0
  const bool b5v = (lane >> 5) & 1;            // gate bit 1
  const int g = (b5v ? 2 : 0) + (b3v ? 1 : 0); // gate id on bits (b5,b3)
  const int p = ((lane >> 4) & 1) * 8 + (lane & 7);  // 4-bit chunk id (b4,b2,b1,b0)
  const int D0 = 8 * p + 2 * g;                // cell-owned dims D0, D0+1
  const int b = blockIdx.x;

  const float* gW = (g == 0) ? Wf : (g == 1) ? Wi : (g == 2) ? Wg : Wo;
  const float* gB = (g == 0) ? bf : (g == 1) ? bi : (g == 2) ? bg : bo;
  const float* gP = (g == 0) ? pf : (g == 1) ? pi_ : (g == 2) ? pg : po;

  // ---- one-time register preloads (INV2PI folded into wx/wh/bq) ----
  vf2 wx[8], wh[8];
  {
    const vf2* pxw = (const vf2*)(Wq + r * 256 + 16 * c);
    const vf2* phw = (const vf2*)(Wq + r * 256 + 128 + 16 * c);
#pragma unroll
    for (int j = 0; j < 8; ++j) { wx[j] = pxw[j] * INV2PI; wh[j] = phw[j] * INV2PI; }
  }
  const float bqv = bq[r] * INV2PI;

  const float amul = (g == 2) ? 2.0f : 1.0f;   // tanh = 2*sigmoid(2x)-1
  const float oadd = (g == 2) ? -1.0f : 0.0f;
  const float ksc  = -amul * LOG2E;            // folded: act = exp2(acc)

  // gate-GEMM weights indexed by XOR-DISTANCE m: pair m <-> dims 8p+2(g^m)
  vf2 wg2[8][4];
  vf2 bias2[4];
#pragma unroll
  for (int m = 0; m < 4; ++m) {
    const int dm = 8 * p + 2 * (g ^ m);
#pragma unroll
    for (int w = 0; w < 8; ++w) {
      wg2[w][m].x = gW[dm * 8 + w] * ksc;
      wg2[w][m].y = gW[(dm + 1) * 8 + w] * ksc;
    }
    bias2[m].x = gB[dm] * ksc;
    bias2[m].y = gB[dm + 1] * ksc;
  }
  vf2 cbsb[8]; float C1[8], S1[8];
#pragma unroll
  for (int w = 0; w < 8; ++w) {
    float th0 = gP[w], th1 = gP[8 + w];
    cbsb[w].x = cosf(th0); cbsb[w].y = sinf(th0);
    C1[w] = cosf(th1); S1[w] = sinf(th1);
  }

  // state
  vf2 c2; c2.x = 0.f; c2.y = 0.f;
  vf2 h2v; h2v.x = 0.f; h2v.y = 0.f;
  float4 hh0 = {0,0,0,0}, hh1 = {0,0,0,0}, hh2 = {0,0,0,0}, hh3 = {0,0,0,0};

  const float* xg = X + (size_t)b * IN_DIM + 16 * c;
  float* outp = out + (size_t)b * HID + D0;
  char* hb    = (char*)h_sw + 80 * c;                          // read base (line c)
  char* hwp   = (char*)h_sw + 80 * (D0 >> 4) + 4 * (D0 & 15);  // write addr (dims D0,D0+1)

  // xp for t=0
  float xp_cur;
  {
    const float4* x0_ = (const float4*)xg;
    float4 a0 = x0_[0], a1 = x0_[1], a2 = x0_[2], a3 = x0_[3];
    vf2 t0 = wx[0] * (vf2){a0.x, a0.y} + wx[1] * (vf2){a0.z, a0.w};
    vf2 t1 = wx[2] * (vf2){a1.x, a1.y} + wx[3] * (vf2){a1.z, a1.w};
    vf2 t2 = wx[4] * (vf2){a2.x, a2.y} + wx[5] * (vf2){a2.z, a2.w};
    vf2 t3 = wx[6] * (vf2){a3.x, a3.y} + wx[7] * (vf2){a3.z, a3.w};
    vf2 ax = (t0 + t1) + (t2 + t3);
    xp_cur = ax.x + ax.y;
  }

#pragma unroll 1
  for (int t = 0; t < SEQ; ++t) {
    // ---- 1. chain: q_in dot (tree) + row8 DPP reduce + sincos ----
    float zz;
    {
      vf2 t0 = wh[0] * (vf2){hh0.x, hh0.y} + wh[1] * (vf2){hh0.z, hh0.w};
      vf2 t1 = wh[2] * (vf2){hh1.x, hh1.y} + wh[3] * (vf2){hh1.z, hh1.w};
      vf2 t2 = wh[4] * (vf2){hh2.x, hh2.y} + wh[5] * (vf2){hh2.z, hh2.w};
      vf2 t3 = wh[6] * (vf2){hh3.x, hh3.y} + wh[7] * (vf2){hh3.z, hh3.w};
      vf2 aq = ((t0 + t1) + (t2 + t3)) + (vf2){xp_cur, 0.0f};
      float s_ = aq.x + aq.y;
      s_ = dpp_add<0xB1>(s_); s_ = dpp_add<0x4E>(s_); s_ = dpp_add<0x141>(s_);
      zz = s_ + bqv;                      // already in revolutions
    }
    float szv = sin2pi_f(zz), czv = cos2pi_f(zz);

    // ---- off-chain: X(t+1) loads (consumed at step tail) ----
    float4 xl0, xl1, xl2, xl3;
    {
      const int tn = (t + 1 < SEQ) ? t + 1 : SEQ - 1;
      const float4* xn_ = (const float4*)(xg + (size_t)tn * (BATCH * IN_DIM));
      xl0 = xn_[0]; xl1 = xn_[1]; xl2 = xn_[2]; xl3 = xn_[3];
    }

    // ---- 2. broadcast (c,s) of all 8 wires via readlane -> SGPRs ----
    float cqs[8], sqs[8];
#pragma unroll
    for (int w = 0; w < 8; ++w) { cqs[w] = rdlane(czv, 8 * w); sqs[w] = rdlane(szv, 8 * w); }

    // ---- 3. TM chain + fused gate GEMM (bit-identical math to R3) ----
    vf2 acc0 = bias2[0], acc1 = bias2[1], acc2 = bias2[2], acc3 = bias2[3];
    float u_, d_, P_, R_;
    {
      vf2 KA0 = cbsb[0] * cqs[0];
      u_ = C1[0]; d_ = C1[0] * KA0.x;
      P_ = -S1[0] * KA0.y; R_ = -S1[0] * sqs[0];
    }
#pragma unroll
    for (int w = 1; w < 8; ++w) {
      vf2 KA = cbsb[w] * cqs[w];          // (K, A2)
      float K_ = KA.x, A2_ = KA.y, B2_ = sqs[w];
      float Md = fmaf(A2_, P_, d_);
      float MP = fmaf(A2_, d_, P_);
      float Mu = fmaf(K_, u_, -(B2_ * R_));
      float MR = fmaf(B2_, u_, K_ * R_);
      acc0 += Md * wg2[w - 1][0]; acc1 += Md * wg2[w - 1][1];
      acc2 += Md * wg2[w - 1][2]; acc3 += Md * wg2[w - 1][3];
      u_ = C1[w] * Md; d_ = C1[w] * Mu;
      P_ = -S1[w] * MP; R_ = -S1[w] * MR;
    }
    float ev7_ = d_ + P_;
    acc0 += ev7_ * wg2[7][0]; acc1 += ev7_ * wg2[7][1];
    acc2 += ev7_ * wg2[7][2]; acc3 += ev7_ * wg2[7][3];

    // ---- 4. activation: bare exp2 (scale folded) -> pairs by xor-distance ----
    vf2 pm0, pm1, pm2, pm3;
    pm0.x = fmaf(rcp_f(1.0f + exp2_f(acc0.x)), amul, oadd);
    pm0.y = fmaf(rcp_f(1.0f + exp2_f(acc0.y)), amul, oadd);
    pm1.x = fmaf(rcp_f(1.0f + exp2_f(acc1.x)), amul, oadd);
    pm1.y = fmaf(rcp_f(1.0f + exp2_f(acc1.y)), amul, oadd);
    pm2.x = fmaf(rcp_f(1.0f + exp2_f(acc2.x)), amul, oadd);
    pm2.y = fmaf(rcp_f(1.0f + exp2_f(acc2.y)), amul, oadd);
    pm3.x = fmaf(rcp_f(1.0f + exp2_f(acc3.x)), amul, oadd);
    pm3.y = fmaf(rcp_f(1.0f + exp2_f(acc3.y)), amul, oadd);

    // ---- 5. gate exchange: pure-VALU cross-lane (no LDS) ----
    // r_m = foreign quarter at gate-xor distance m; partner's pair m is
    // exactly MY dims (D0, D0+1) of gate g^m (weights pre-permuted).
    vf2 r1, r2, r3;
    r1.x = dpp_mov<0x128>(pm1.x);            // ROW_ROR:8 == lane^8
    r1.y = dpp_mov<0x128>(pm1.y);
    r2.x = xor32_f(pm2.x, b5v);              // lane^32
    r2.y = xor32_f(pm2.y, b5v);
    {
      float t0 = dpp_mov<0x128>(pm3.x);      // lane^40 = (lane^8)^32
      float t1 = dpp_mov<0x128>(pm3.y);
      r3.x = xor32_f(t0, b5v);
      r3.y = xor32_f(t1, b5v);
    }
    // map {own, r1, r2, r3} (xor-distance order) -> (f,i,g,o) (gate order):
    // gate q's value = r_{q^g} (own when q==g).
    vf2 fv, iv, gv, ov;
    {
      vf2 lo, hi;
      lo = b3v ? r1 : pm0;  hi = b3v ? r3 : r2;  fv = b5v ? hi : lo;
      lo = b3v ? pm0 : r1;  hi = b3v ? r2 : r3;  iv = b5v ? hi : lo;
      lo = b3v ? r3 : r2;   hi = b3v ? r1 : pm0; gv = b5v ? hi : lo;
      lo = b3v ? r2 : r3;   hi = b3v ? pm0 : r1; ov = b5v ? hi : lo;
    }

    // ---- 6. cell update (dims D0, D0+1) ----
    c2 = fv * c2 + iv * gv;
    h2v.x = ov.x * tanh_f(c2.x);
    h2v.y = ov.y * tanh_f(c2.y);

    // ---- 7. h publish (swizzled 80B lines) + immediate next-step reads ----
    *(vf2*)hwp = h2v;
    hh0 = *(const float4*)(hb);
    hh1 = *(const float4*)(hb + 16);
    hh2 = *(const float4*)(hb + 32);
    hh3 = *(const float4*)(hb + 48);

    // ---- 8. xp tail from xl (vmcnt waits only on loads), then output store ----
    {
      vf2 t0 = wx[0] * (vf2){xl0.x, xl0.y} + wx[1] * (vf2){xl0.z, xl0.w};
      vf2 t1 = wx[2] * (vf2){xl1.x, xl1.y} + wx[3] * (vf2){xl1.z, xl1.w};
      vf2 t2 = wx[4] * (vf2){xl2.x, xl2.y} + wx[5] * (vf2){xl2.z, xl2.w};
      vf2 t3 = wx[6] * (vf2){xl3.x, xl3.y} + wx[7] * (vf2){xl3.z, xl3.w};
      vf2 axn = (t0 + t1) + (t2 + t3);
      xp_cur = axn.x + axn.y;
    }
    *(vf2*)(outp + (size_t)t * (BATCH * HID)) = h2v;
  }

  // hx, cx
  {
    size_t base = (size_t)SEQ * BATCH * HID;
    *(vf2*)(out + base + (size_t)b * HID + D0) = h2v;
    *(vf2*)(out + base + (size_t)BATCH * HID + (size_t)b * HID + D0) = c2;
  }
}

extern "C" void kernel_launch(void* const* d_in, const int* in_sizes, int n_in,
                              void* d_out, int out_size, void* d_ws, size_t ws_size,
                              hipStream_t stream) {
  (void)in_sizes; (void)n_in; (void)out_size; (void)d_ws; (void)ws_size;
  const float* X   = (const float*)d_in[0];
  const float* Wq  = (const float*)d_in[1];
  const float* bq  = (const float*)d_in[2];
  const float* pf  = (const float*)d_in[3];
  const float* pi_ = (const float*)d_in[4];
  const float* pg  = (const float*)d_in[5];
  const float* po  = (const float*)d_in[6];
  const float* Wf  = (const float*)d_in[7];
  const float* bf  = (const float*)d_in[8];
  const float* Wi  = (const float*)d_in[9];
  const float* bi  = (const float*)d_in[10];
  const float* Wg  = (const float*)d_in[11];
  const float* bg  = (const float*)d_in[12];
  const float* Wo  = (const float*)d_in[13];
  const float* bo  = (const float*)d_in[14];
  float* out = (float*)d_out;

  qlstm_kernel<<<BATCH, 64, 0, stream>>>(X, Wq, bq, pf, pi_, pg, po,
                                         Wf, bf, Wi, bi, Wg, bg, Wo, bo, out);
}

// Round 7
// 182.777 us; speedup vs baseline: 1.1902x; 1.1030x over previous
//
#include <hip/hip_runtime.h>

#define SEQ 128
#define BATCH 512
#define IN_DIM 128
#define HID 128

typedef float vf2 __attribute__((ext_vector_type(2)));

#define LOG2E 1.4426950408889634f
#define INV2PI 0.15915494309189535f

__device__ __forceinline__ float rcp_f(float x) { return __builtin_amdgcn_rcpf(x); }
// Guaranteed-native transcendentals (single VOP1 each).
__device__ __forceinline__ float exp2_f(float x) { float r; asm("v_exp_f32 %0, %1" : "=v"(r) : "v"(x)); return r; }
__device__ __forceinline__ float sin2pi_f(float x) { float r; asm("v_sin_f32 %0, %1" : "=v"(r) : "v"(x)); return r; }
__device__ __forceinline__ float cos2pi_f(float x) { float r; asm("v_cos_f32 %0, %1" : "=v"(r) : "v"(x)); return r; }
__device__ __forceinline__ float tanh_f(float x) {
  // tanh(x) = 1 - 2/(exp2(x*2log2e)+1)
  return 1.0f - 2.0f * rcp_f(exp2_f(x * 2.885390082f) + 1.0f);
}

template <int CTRL>
__device__ __forceinline__ float dpp_add(float s) {
  return s + __int_as_float(__builtin_amdgcn_mov_dpp(__float_as_int(s), CTRL, 0xF, 0xF, true));
}
__device__ __forceinline__ float rdlane(float v, int src) {
  return __int_as_float(__builtin_amdgcn_readlane(__float_as_int(v), src));
}

// ONE WAVE per batch element.  R3 structure (best measured: LDS gate exchange)
// with ONE mechanistic fix + one free port:
//  * 2-deep X load pipeline: iter t issues loads for t+2, consumes loads for
//    t+1 (issued at iter t-1 top, BEFORE store(t-1)).  vmcnt retires in FIFO
//    order, so the consumed loads are the OLDEST outstanding vmem ops and the
//    compiler emits a counted s_waitcnt vmcnt(5) -- the previous iteration's
//    global store is never waited on.  (R3 waited vmcnt(0) every step, putting
//    a full store round-trip on the critical path.)
//  * h tile in padded 80-byte LDS lines (R6-verified): conflict-free reads.
// TM recursion / gate GEMM / activation arithmetic bit-identical to R3.
__global__ __launch_bounds__(64) void qlstm_kernel(
    const float* __restrict__ X, const float* __restrict__ Wq, const float* __restrict__ bq,
    const float* __restrict__ pf, const float* __restrict__ pi_, const float* __restrict__ pg,
    const float* __restrict__ po, const float* __restrict__ Wf, const float* __restrict__ bf,
    const float* __restrict__ Wi, const float* __restrict__ bi, const float* __restrict__ Wg,
    const float* __restrict__ bg, const float* __restrict__ Wo, const float* __restrict__ bo,
    float* __restrict__ out)
{
  __shared__ __align__(16) float h_sw[160];      // 8 lines x (16 floats + 16B pad) = 640 B
  __shared__ __align__(16) float gsh[4 * HID];   // [gate][128]

  const int lane = threadIdx.x;
  const int r = lane >> 3, c = lane & 7;         // dot roles: wire r, dims 16c..16c+15
  const int g = lane >> 4, p = lane & 15;        // gate roles: gate g, act dims 8p..8p+7
  const int b = blockIdx.x;
  const int D0 = 2 * lane;                       // cell-owned dims D0, D0+1

  const float* gW = (g == 0) ? Wf : (g == 1) ? Wi : (g == 2) ? Wg : Wo;
  const float* gB = (g == 0) ? bf : (g == 1) ? bi : (g == 2) ? bg : bo;
  const float* gP = (g == 0) ? pf : (g == 1) ? pi_ : (g == 2) ? pg : po;

  // ---- one-time register preloads (INV2PI folded into wx/wh/bq) ----
  vf2 wx[8], wh[8];
  {
    const vf2* pxw = (const vf2*)(Wq + r * 256 + 16 * c);
    const vf2* phw = (const vf2*)(Wq + r * 256 + 128 + 16 * c);
#pragma unroll
    for (int j = 0; j < 8; ++j) { wx[j] = pxw[j] * INV2PI; wh[j] = phw[j] * INV2PI; }
  }
  const float bqv = bq[r] * INV2PI;

  const float amul = (g == 2) ? 2.0f : 1.0f;     // tanh = 2*sigmoid(2x)-1
  const float oadd = (g == 2) ? -1.0f : 0.0f;
  const float ksc  = -amul * LOG2E;              // folded: act = exp2(acc)

  vf2 wg2[8][4];
#pragma unroll
  for (int w = 0; w < 8; ++w)
#pragma unroll
    for (int j = 0; j < 4; ++j) {
      wg2[w][j].x = gW[(8 * p + 2 * j)     * 8 + w] * ksc;
      wg2[w][j].y = gW[(8 * p + 2 * j + 1) * 8 + w] * ksc;
    }
  vf2 bias2[4];
#pragma unroll
  for (int j = 0; j < 4; ++j) {
    bias2[j].x = gB[8 * p + 2 * j]     * ksc;
    bias2[j].y = gB[8 * p + 2 * j + 1] * ksc;
  }
  vf2 cbsb[8]; float C1[8], S1[8];
#pragma unroll
  for (int w = 0; w < 8; ++w) {
    float th0 = gP[w], th1 = gP[8 + w];
    cbsb[w].x = cosf(th0); cbsb[w].y = sinf(th0);
    C1[w] = cosf(th1); S1[w] = sinf(th1);
  }

  // state
  vf2 c2; c2.x = 0.f; c2.y = 0.f;
  vf2 h2v; h2v.x = 0.f; h2v.y = 0.f;
  float4 hh0 = {0,0,0,0}, hh1 = {0,0,0,0}, hh2 = {0,0,0,0}, hh3 = {0,0,0,0};

  const float* xg = X + (size_t)b * IN_DIM + 16 * c;
  float* outp = out + (size_t)b * HID + D0;
  char* hb    = (char*)h_sw + 80 * c;                          // read base (line c)
  char* hwp   = (char*)h_sw + 80 * (D0 >> 4) + 4 * (D0 & 15);  // write addr (dims D0,D0+1)

  // ---- prologue: xp(t=0) + X(1) into pipeline buffer A ----
  float xp_cur;
  float4 xA0, xA1, xA2, xA3, xB0, xB1, xB2, xB3;
  {
    const float4* x0_ = (const float4*)xg;
    float4 a0 = x0_[0], a1 = x0_[1], a2 = x0_[2], a3 = x0_[3];
    vf2 t0 = wx[0] * (vf2){a0.x, a0.y} + wx[1] * (vf2){a0.z, a0.w};
    vf2 t1 = wx[2] * (vf2){a1.x, a1.y} + wx[3] * (vf2){a1.z, a1.w};
    vf2 t2 = wx[4] * (vf2){a2.x, a2.y} + wx[5] * (vf2){a2.z, a2.w};
    vf2 t3 = wx[6] * (vf2){a3.x, a3.y} + wx[7] * (vf2){a3.z, a3.w};
    vf2 ax = (t0 + t1) + (t2 + t3);
    xp_cur = ax.x + ax.y;
    const float4* x1_ = (const float4*)(xg + (size_t)1 * (BATCH * IN_DIM));
    xA0 = x1_[0]; xA1 = x1_[1]; xA2 = x1_[2]; xA3 = x1_[3];
  }

// XC*: buffer holding X(T+1), consumed at this step's tail.
// XL*: buffer to fill with X(TL) where TL = min(T+2, SEQ-1).
#define QSTEP(XC0, XC1, XC2, XC3, XL0, XL1, XL2, XL3, T)                              \
  {                                                                                   \
    /* ---- 0. issue X(T+2) loads: oldest-consumed-first vmem discipline ---- */      \
    {                                                                                 \
      const int tl_ = ((T) + 2 < SEQ) ? (T) + 2 : (SEQ - 1);                          \
      const float4* xn_ = (const float4*)(xg + (size_t)tl_ * (BATCH * IN_DIM));       \
      XL0 = xn_[0]; XL1 = xn_[1]; XL2 = xn_[2]; XL3 = xn_[3];                         \
    }                                                                                 \
    /* ---- 1. chain: q_in dot (tree) + row8 DPP reduce + sincos ---- */              \
    float zz;                                                                         \
    {                                                                                 \
      vf2 t0 = wh[0] * (vf2){hh0.x, hh0.y} + wh[1] * (vf2){hh0.z, hh0.w};             \
      vf2 t1 = wh[2] * (vf2){hh1.x, hh1.y} + wh[3] * (vf2){hh1.z, hh1.w};             \
      vf2 t2 = wh[4] * (vf2){hh2.x, hh2.y} + wh[5] * (vf2){hh2.z, hh2.w};             \
      vf2 t3 = wh[6] * (vf2){hh3.x, hh3.y} + wh[7] * (vf2){hh3.z, hh3.w};             \
      vf2 aq = ((t0 + t1) + (t2 + t3)) + (vf2){xp_cur, 0.0f};                         \
      float s_ = aq.x + aq.y;                                                         \
      s_ = dpp_add<0xB1>(s_); s_ = dpp_add<0x4E>(s_); s_ = dpp_add<0x141>(s_);        \
      zz = s_ + bqv;                      /* already in revolutions */                \
    }                                                                                 \
    float szv = sin2pi_f(zz), czv = cos2pi_f(zz);                                     \
    /* ---- 2. broadcast (c,s) of all 8 wires via readlane -> SGPRs ---- */           \
    float cqs[8], sqs[8];                                                             \
    _Pragma("unroll")                                                                 \
    for (int w = 0; w < 8; ++w) { cqs[w] = rdlane(czv, 8 * w); sqs[w] = rdlane(szv, 8 * w); } \
    /* ---- 3. TM chain + fused gate GEMM (bit-identical to R3) ---- */               \
    vf2 acc0 = bias2[0], acc1 = bias2[1], acc2 = bias2[2], acc3 = bias2[3];           \
    float u_, d_, P_, R_;                                                             \
    {                                                                                 \
      vf2 KA0 = cbsb[0] * cqs[0];                                                     \
      u_ = C1[0]; d_ = C1[0] * KA0.x;                                                 \
      P_ = -S1[0] * KA0.y; R_ = -S1[0] * sqs[0];                                      \
    }                                                                                 \
    _Pragma("unroll")                                                                 \
    for (int w = 1; w < 8; ++w) {                                                     \
      vf2 KA = cbsb[w] * cqs[w];                                                      \
      float K_ = KA.x, A2_ = KA.y, B2_ = sqs[w];                                      \
      float Md = fmaf(A2_, P_, d_);                                                   \
      float MP = fmaf(A2_, d_, P_);                                                   \
      float Mu = fmaf(K_, u_, -(B2_ * R_));                                           \
      float MR = fmaf(B2_, u_, K_ * R_);                                              \
      acc0 += Md * wg2[w - 1][0]; acc1 += Md * wg2[w - 1][1];                         \
      acc2 += Md * wg2[w - 1][2]; acc3 += Md * wg2[w - 1][3];                         \
      u_ = C1[w] * Md; d_ = C1[w] * Mu;                                               \
      P_ = -S1[w] * MP; R_ = -S1[w] * MR;                                             \
    }                                                                                 \
    float ev7_ = d_ + P_;                                                             \
    acc0 += ev7_ * wg2[7][0]; acc1 += ev7_ * wg2[7][1];                               \
    acc2 += ev7_ * wg2[7][2]; acc3 += ev7_ * wg2[7][3];                               \
    /* ---- 4. activation: bare exp2 (scale folded into weights) ---- */              \
    float av_[8] = {acc0.x, acc0.y, acc1.x, acc1.y, acc2.x, acc2.y, acc3.x, acc3.y};  \
    float o8[8];                                                                      \
    _Pragma("unroll")                                                                 \
    for (int k = 0; k < 8; ++k) {                                                     \
      float e_ = exp2_f(av_[k]);                                                      \
      o8[k] = fmaf(rcp_f(1.0f + e_), amul, oadd);                                     \
    }                                                                                 \
    /* ---- 5. gate exchange via LDS (parallel pipe; beats VALU per R5/R6) ---- */    \
    {                                                                                 \
      float4* gp4 = (float4*)(gsh + g * HID + 8 * p);                                 \
      float4 w0; w0.x = o8[0]; w0.y = o8[1]; w0.z = o8[2]; w0.w = o8[3];              \
      float4 w1; w1.x = o8[4]; w1.y = o8[5]; w1.z = o8[6]; w1.w = o8[7];              \
      gp4[0] = w0; gp4[1] = w1;                                                       \
    }                                                                                 \
    vf2 fv = *(const vf2*)(gsh + 0 * HID + D0);                                       \
    vf2 iv = *(const vf2*)(gsh + 1 * HID + D0);                                       \
    vf2 gv = *(const vf2*)(gsh + 2 * HID + D0);                                       \
    vf2 ov = *(const vf2*)(gsh + 3 * HID + D0);                                       \
    /* ---- 6. cell update (dims D0, D0+1) ---- */                                    \
    c2 = fv * c2 + iv * gv;                                                           \
    h2v.x = ov.x * tanh_f(c2.x);                                                      \
    h2v.y = ov.y * tanh_f(c2.y);                                                      \
    /* ---- 7. h publish (padded lines) + immediate next-step reads ---- */           \
    *(vf2*)hwp = h2v;                                                                 \
    hh0 = *(const float4*)(hb);                                                       \
    hh1 = *(const float4*)(hb + 16);                                                  \
    hh2 = *(const float4*)(hb + 32);                                                  \
    hh3 = *(const float4*)(hb + 48);                                                  \
    /* ---- 8. xp tail from XC (counted vmcnt: XC are the OLDEST vmem) ---- */        \
    {                                                                                 \
      vf2 t0 = wx[0] * (vf2){XC0.x, XC0.y} + wx[1] * (vf2){XC0.z, XC0.w};             \
      vf2 t1 = wx[2] * (vf2){XC1.x, XC1.y} + wx[3] * (vf2){XC1.z, XC1.w};             \
      vf2 t2 = wx[4] * (vf2){XC2.x, XC2.y} + wx[5] * (vf2){XC2.z, XC2.w};             \
      vf2 t3 = wx[6] * (vf2){XC3.x, XC3.y} + wx[7] * (vf2){XC3.z, XC3.w};             \
      vf2 axn = (t0 + t1) + (t2 + t3);                                                \
      xp_cur = axn.x + axn.y;                                                         \
    }                                                                                 \
    *(vf2*)(outp + (size_t)(T) * (BATCH * HID)) = h2v;                                \
  }

#pragma unroll 1
  for (int tt = 0; tt < SEQ; tt += 2) {
    QSTEP(xA0, xA1, xA2, xA3, xB0, xB1, xB2, xB3, tt);
    QSTEP(xB0, xB1, xB2, xB3, xA0, xA1, xA2, xA3, tt + 1);
  }
#undef QSTEP

  // hx, cx
  {
    size_t base = (size_t)SEQ * BATCH * HID;
    *(vf2*)(out + base + (size_t)b * HID + D0) = h2v;
    *(vf2*)(out + base + (size_t)BATCH * HID + (size_t)b * HID + D0) = c2;
  }
}

extern "C" void kernel_launch(void* const* d_in, const int* in_sizes, int n_in,
                              void* d_out, int out_size, void* d_ws, size_t ws_size,
                              hipStream_t stream) {
  (void)in_sizes; (void)n_in; (void)out_size; (void)d_ws; (void)ws_size;
  const float* X   = (const float*)d_in[0];
  const float* Wq  = (const float*)d_in[1];
  const float* bq  = (const float*)d_in[2];
  const float* pf  = (const float*)d_in[3];
  const float* pi_ = (const float*)d_in[4];
  const float* pg  = (const float*)d_in[5];
  const float* po  = (const float*)d_in[6];
  const float* Wf  = (const float*)d_in[7];
  const float* bf  = (const float*)d_in[8];
  const float* Wi  = (const float*)d_in[9];
  const float* bi  = (const float*)d_in[10];
  const float* Wg  = (const float*)d_in[11];
  const float* bg  = (const float*)d_in[12];
  const float* Wo  = (const float*)d_in[13];
  const float* bo  = (const float*)d_in[14];
  float* out = (float*)d_out;

  qlstm_kernel<<<BATCH, 64, 0, stream>>>(X, Wq, bq, pf, pi_, pg, po,
                                         Wf, bf, Wi, bi, Wg, bg, Wo, bo, out);
}

// Round 8
// 173.336 us; speedup vs baseline: 1.2550x; 1.0545x over previous
//
#include <hip/hip_runtime.h>

#define SEQ 128
#define BATCH 512
#define IN_DIM 128
#define HID 128

typedef float vf2 __attribute__((ext_vector_type(2)));

#define LOG2E 1.4426950408889634f
#define INV2PI 0.15915494309189535f

__device__ __forceinline__ float rcp_f(float x) { return __builtin_amdgcn_rcpf(x); }
// Guaranteed-native transcendentals (single VOP1 each).
__device__ __forceinline__ float exp2_f(float x) { float r; asm("v_exp_f32 %0, %1" : "=v"(r) : "v"(x)); return r; }
__device__ __forceinline__ float sin2pi_f(float x) { float r; asm("v_sin_f32 %0, %1" : "=v"(r) : "v"(x)); return r; }
__device__ __forceinline__ float cos2pi_f(float x) { float r; asm("v_cos_f32 %0, %1" : "=v"(r) : "v"(x)); return r; }
__device__ __forceinline__ float tanh_f(float x) {
  // tanh(x) = 1 - 2/(exp2(x*2log2e)+1)
  return 1.0f - 2.0f * rcp_f(exp2_f(x * 2.885390082f) + 1.0f);
}

template <int CTRL>
__device__ __forceinline__ float dpp_add(float s) {
  return s + __int_as_float(__builtin_amdgcn_mov_dpp(__float_as_int(s), CTRL, 0xF, 0xF, true));
}
__device__ __forceinline__ float rdlane(float v, int src) {
  return __int_as_float(__builtin_amdgcn_readlane(__float_as_int(v), src));
}
__device__ __forceinline__ float bperm_f(int byte_addr, float v) {
  return __int_as_float(__builtin_amdgcn_ds_bpermute(byte_addr, __float_as_int(v)));
}

// ONE WAVE per batch element.  R7 base (counted-vmcnt X pipeline, LDS gate
// exchange) with two stall-targeted changes:
//  * h exchange via 16x ds_bpermute (register crossbar, single ~120cyc pass)
//    instead of LDS write->read RAW round trip (~200-240cyc).  h never touches
//    LDS memory; dot arithmetic order bit-identical (bpermute delivers the
//    same values the LDS trip did).
//  * xp-tail (16 FMA + counted vmcnt wait) moved BETWEEN the gate ds_read
//    issue and the gate use -- covers the gate RAW trip (previously naked);
//    the h-side bpermute pass is covered by out-store + branch + X-issue.
// TM recursion / gate GEMM / activation arithmetic bit-identical to R3/R7.
__global__ __launch_bounds__(64) void qlstm_kernel(
    const float* __restrict__ X, const float* __restrict__ Wq, const float* __restrict__ bq,
    const float* __restrict__ pf, const float* __restrict__ pi_, const float* __restrict__ pg,
    const float* __restrict__ po, const float* __restrict__ Wf, const float* __restrict__ bf,
    const float* __restrict__ Wi, const float* __restrict__ bi, const float* __restrict__ Wg,
    const float* __restrict__ bg, const float* __restrict__ Wo, const float* __restrict__ bo,
    float* __restrict__ out)
{
  __shared__ __align__(16) float gsh[4 * HID];   // [gate][128] -- gate exchange only

  const int lane = threadIdx.x;
  const int r = lane >> 3, c = lane & 7;         // dot roles: wire r, dims 16c..16c+15
  const int g = lane >> 4, p = lane & 15;        // gate roles: gate g, act dims 8p..8p+7
  const int b = blockIdx.x;
  const int D0 = 2 * lane;                       // cell-owned dims D0, D0+1

  const float* gW = (g == 0) ? Wf : (g == 1) ? Wi : (g == 2) ? Wg : Wo;
  const float* gB = (g == 0) ? bf : (g == 1) ? bi : (g == 2) ? bg : bo;
  const float* gP = (g == 0) ? pf : (g == 1) ? pi_ : (g == 2) ? pg : po;

  // ---- one-time register preloads (INV2PI folded into wx/wh/bq) ----
  vf2 wx[8], wh[8];
  {
    const vf2* pxw = (const vf2*)(Wq + r * 256 + 16 * c);
    const vf2* phw = (const vf2*)(Wq + r * 256 + 128 + 16 * c);
#pragma unroll
    for (int j = 0; j < 8; ++j) { wx[j] = pxw[j] * INV2PI; wh[j] = phw[j] * INV2PI; }
  }
  const float bqv = bq[r] * INV2PI;

  const float amul = (g == 2) ? 2.0f : 1.0f;     // tanh = 2*sigmoid(2x)-1
  const float oadd = (g == 2) ? -1.0f : 0.0f;
  const float ksc  = -amul * LOG2E;              // folded: act = exp2(acc)

  vf2 wg2[8][4];
#pragma unroll
  for (int w = 0; w < 8; ++w)
#pragma unroll
    for (int j = 0; j < 4; ++j) {
      wg2[w][j].x = gW[(8 * p + 2 * j)     * 8 + w] * ksc;
      wg2[w][j].y = gW[(8 * p + 2 * j + 1) * 8 + w] * ksc;
    }
  vf2 bias2[4];
#pragma unroll
  for (int j = 0; j < 4; ++j) {
    bias2[j].x = gB[8 * p + 2 * j]     * ksc;
    bias2[j].y = gB[8 * p + 2 * j + 1] * ksc;
  }
  vf2 cbsb[8]; float C1[8], S1[8];
#pragma unroll
  for (int w = 0; w < 8; ++w) {
    float th0 = gP[w], th1 = gP[8 + w];
    cbsb[w].x = cosf(th0); cbsb[w].y = sinf(th0);
    C1[w] = cosf(th1); S1[w] = sinf(th1);
  }

  // bpermute byte-addresses for the h gather: lane (r,c) reads lanes 8c+j
  int bpa[8];
#pragma unroll
  for (int j = 0; j < 8; ++j) bpa[j] = 4 * (8 * c + j);

  // state
  vf2 c2; c2.x = 0.f; c2.y = 0.f;
  vf2 h2v; h2v.x = 0.f; h2v.y = 0.f;
  float hx[8], hy[8];                            // gathered h for the dot (regs)
#pragma unroll
  for (int j = 0; j < 8; ++j) { hx[j] = 0.f; hy[j] = 0.f; }

  const float* xg = X + (size_t)b * IN_DIM + 16 * c;
  float* outp = out + (size_t)b * HID + D0;

  // ---- prologue: xp(t=0) + X(1) into pipeline buffer A ----
  float xp_cur;
  float4 xA0, xA1, xA2, xA3, xB0, xB1, xB2, xB3;
  {
    const float4* x0_ = (const float4*)xg;
    float4 a0 = x0_[0], a1 = x0_[1], a2 = x0_[2], a3 = x0_[3];
    vf2 t0 = wx[0] * (vf2){a0.x, a0.y} + wx[1] * (vf2){a0.z, a0.w};
    vf2 t1 = wx[2] * (vf2){a1.x, a1.y} + wx[3] * (vf2){a1.z, a1.w};
    vf2 t2 = wx[4] * (vf2){a2.x, a2.y} + wx[5] * (vf2){a2.z, a2.w};
    vf2 t3 = wx[6] * (vf2){a3.x, a3.y} + wx[7] * (vf2){a3.z, a3.w};
    vf2 ax = (t0 + t1) + (t2 + t3);
    xp_cur = ax.x + ax.y;
    const float4* x1_ = (const float4*)(xg + (size_t)1 * (BATCH * IN_DIM));
    xA0 = x1_[0]; xA1 = x1_[1]; xA2 = x1_[2]; xA3 = x1_[3];
  }

// XC*: buffer holding X(T+1), consumed at this step's xp-tail.
// XL*: buffer to fill with X(TL) where TL = min(T+2, SEQ-1).
#define QSTEP(XC0, XC1, XC2, XC3, XL0, XL1, XL2, XL3, T)                              \
  {                                                                                   \
    /* ---- 0. issue X(T+2) loads: oldest-consumed-first vmem discipline ---- */      \
    {                                                                                 \
      const int tl_ = ((T) + 2 < SEQ) ? (T) + 2 : (SEQ - 1);                          \
      const float4* xn_ = (const float4*)(xg + (size_t)tl_ * (BATCH * IN_DIM));       \
      XL0 = xn_[0]; XL1 = xn_[1]; XL2 = xn_[2]; XL3 = xn_[3];                         \
    }                                                                                 \
    /* ---- 1. chain: q_in dot (tree) + row8 DPP reduce + sincos ---- */              \
    float zz;                                                                         \
    {                                                                                 \
      vf2 t0 = wh[0] * (vf2){hx[0], hy[0]} + wh[1] * (vf2){hx[1], hy[1]};             \
      vf2 t1 = wh[2] * (vf2){hx[2], hy[2]} + wh[3] * (vf2){hx[3], hy[3]};             \
      vf2 t2 = wh[4] * (vf2){hx[4], hy[4]} + wh[5] * (vf2){hx[5], hy[5]};             \
      vf2 t3 = wh[6] * (vf2){hx[6], hy[6]} + wh[7] * (vf2){hx[7], hy[7]};             \
      vf2 aq = ((t0 + t1) + (t2 + t3)) + (vf2){xp_cur, 0.0f};                         \
      float s_ = aq.x + aq.y;                                                         \
      s_ = dpp_add<0xB1>(s_); s_ = dpp_add<0x4E>(s_); s_ = dpp_add<0x141>(s_);        \
      zz = s_ + bqv;                      /* already in revolutions */                \
    }                                                                                 \
    float szv = sin2pi_f(zz), czv = cos2pi_f(zz);                                     \
    /* ---- 2. broadcast (c,s) of all 8 wires via readlane -> SGPRs ---- */           \
    float cqs[8], sqs[8];                                                             \
    _Pragma("unroll")                                                                 \
    for (int w = 0; w < 8; ++w) { cqs[w] = rdlane(czv, 8 * w); sqs[w] = rdlane(szv, 8 * w); } \
    /* ---- 3. TM chain + fused gate GEMM (bit-identical to R3) ---- */               \
    vf2 acc0 = bias2[0], acc1 = bias2[1], acc2 = bias2[2], acc3 = bias2[3];           \
    float u_, d_, P_, R_;                                                             \
    {                                                                                 \
      vf2 KA0 = cbsb[0] * cqs[0];                                                     \
      u_ = C1[0]; d_ = C1[0] * KA0.x;                                                 \
      P_ = -S1[0] * KA0.y; R_ = -S1[0] * sqs[0];                                      \
    }                                                                                 \
    _Pragma("unroll")                                                                 \
    for (int w = 1; w < 8; ++w) {                                                     \
      vf2 KA = cbsb[w] * cqs[w];                                                      \
      float K_ = KA.x, A2_ = KA.y, B2_ = sqs[w];                                      \
      float Md = fmaf(A2_, P_, d_);                                                   \
      float MP = fmaf(A2_, d_, P_);                                                   \
      float Mu = fmaf(K_, u_, -(B2_ * R_));                                           \
      float MR = fmaf(B2_, u_, K_ * R_);                                              \
      acc0 += Md * wg2[w - 1][0]; acc1 += Md * wg2[w - 1][1];                         \
      acc2 += Md * wg2[w - 1][2]; acc3 += Md * wg2[w - 1][3];                         \
      u_ = C1[w] * Md; d_ = C1[w] * Mu;                                               \
      P_ = -S1[w] * MP; R_ = -S1[w] * MR;                                             \
    }                                                                                 \
    float ev7_ = d_ + P_;                                                             \
    acc0 += ev7_ * wg2[7][0]; acc1 += ev7_ * wg2[7][1];                               \
    acc2 += ev7_ * wg2[7][2]; acc3 += ev7_ * wg2[7][3];                               \
    /* ---- 4. activation: bare exp2 (scale folded into weights) ---- */              \
    float av_[8] = {acc0.x, acc0.y, acc1.x, acc1.y, acc2.x, acc2.y, acc3.x, acc3.y};  \
    float o8[8];                                                                      \
    _Pragma("unroll")                                                                 \
    for (int k = 0; k < 8; ++k) {                                                     \
      float e_ = exp2_f(av_[k]);                                                      \
      o8[k] = fmaf(rcp_f(1.0f + e_), amul, oadd);                                     \
    }                                                                                 \
    /* ---- 5. gate exchange via LDS; reads issued immediately ---- */                \
    {                                                                                 \
      float4* gp4 = (float4*)(gsh + g * HID + 8 * p);                                 \
      float4 w0; w0.x = o8[0]; w0.y = o8[1]; w0.z = o8[2]; w0.w = o8[3];              \
      float4 w1; w1.x = o8[4]; w1.y = o8[5]; w1.z = o8[6]; w1.w = o8[7];              \
      gp4[0] = w0; gp4[1] = w1;                                                       \
    }                                                                                 \
    vf2 fv = *(const vf2*)(gsh + 0 * HID + D0);                                       \
    vf2 iv = *(const vf2*)(gsh + 1 * HID + D0);                                       \
    vf2 gv = *(const vf2*)(gsh + 2 * HID + D0);                                       \
    vf2 ov = *(const vf2*)(gsh + 3 * HID + D0);                                       \
    /* ---- 6. xp tail from XC (counted vmcnt) -- COVERS the gate RAW trip ---- */    \
    {                                                                                 \
      vf2 t0 = wx[0] * (vf2){XC0.x, XC0.y} + wx[1] * (vf2){XC0.z, XC0.w};             \
      vf2 t1 = wx[2] * (vf2){XC1.x, XC1.y} + wx[3] * (vf2){XC1.z, XC1.w};             \
      vf2 t2 = wx[4] * (vf2){XC2.x, XC2.y} + wx[5] * (vf2){XC2.z, XC2.w};             \
      vf2 t3 = wx[6] * (vf2){XC3.x, XC3.y} + wx[7] * (vf2){XC3.z, XC3.w};             \
      vf2 axn = (t0 + t1) + (t2 + t3);                                                \
      xp_cur = axn.x + axn.y;                                                         \
    }                                                                                 \
    /* ---- 7. cell update (dims D0, D0+1) ---- */                                    \
    c2 = fv * c2 + iv * gv;                                                           \
    h2v.x = ov.x * tanh_f(c2.x);                                                      \
    h2v.y = ov.y * tanh_f(c2.y);                                                      \
    /* ---- 8. h exchange: 16x ds_bpermute (register crossbar, no RAW) ---- */        \
    _Pragma("unroll")                                                                 \
    for (int j = 0; j < 8; ++j) {                                                     \
      hx[j] = bperm_f(bpa[j], h2v.x);                                                 \
      hy[j] = bperm_f(bpa[j], h2v.y);                                                 \
    }                                                                                 \
    /* ---- 9. output store (covers the bpermute pass) ---- */                        \
    *(vf2*)(outp + (size_t)(T) * (BATCH * HID)) = h2v;                                \
  }

#pragma unroll 1
  for (int tt = 0; tt < SEQ; tt += 2) {
    QSTEP(xA0, xA1, xA2, xA3, xB0, xB1, xB2, xB3, tt);
    QSTEP(xB0, xB1, xB2, xB3, xA0, xA1, xA2, xA3, tt + 1);
  }
#undef QSTEP

  // hx, cx
  {
    size_t base = (size_t)SEQ * BATCH * HID;
    *(vf2*)(out + base + (size_t)b * HID + D0) = h2v;
    *(vf2*)(out + base + (size_t)BATCH * HID + (size_t)b * HID + D0) = c2;
  }
}

extern "C" void kernel_launch(void* const* d_in, const int* in_sizes, int n_in,
                              void* d_out, int out_size, void* d_ws, size_t ws_size,
                              hipStream_t stream) {
  (void)in_sizes; (void)n_in; (void)out_size; (void)d_ws; (void)ws_size;
  const float* X   = (const float*)d_in[0];
  const float* Wq  = (const float*)d_in[1];
  const float* bq  = (const float*)d_in[2];
  const float* pf  = (const float*)d_in[3];
  const float* pi_ = (const float*)d_in[4];
  const float* pg  = (const float*)d_in[5];
  const float* po  = (const float*)d_in[6];
  const float* Wf  = (const float*)d_in[7];
  const float* bf  = (const float*)d_in[8];
  const float* Wi  = (const float*)d_in[9];
  const float* bi  = (const float*)d_in[10];
  const float* Wg  = (const float*)d_in[11];
  const float* bg  = (const float*)d_in[12];
  const float* Wo  = (const float*)d_in[13];
  const float* bo  = (const float*)d_in[14];
  float* out = (float*)d_out;

  qlstm_kernel<<<BATCH, 64, 0, stream>>>(X, Wq, bq, pf, pi_, pg, po,
                                         Wf, bf, Wi, bi, Wg, bg, Wo, bo, out);
}